// Round 2
// baseline (4617.978 us; speedup 1.0000x reference)
//
#include <hip/hip_runtime.h>
#include <hip/hip_cooperative_groups.h>
#include <math.h>

namespace cg = cooperative_groups;

#define B_ 32
#define T_ 64
#define V_ 32000
#define D_ 512
#define E_ 1024
#define H_ 1024
#define G4_ 4096   // 4*H
#define ED_ 1536   // E + D
#define M_ 2048    // T*B

typedef unsigned short u16;

using bf16x8 = __attribute__((ext_vector_type(8))) short;
using f32x4  = __attribute__((ext_vector_type(4))) float;

// fp32 -> bf16 (RNE) and back, bit-level (values here are finite/normal)
__device__ __forceinline__ u16 f2bf(float x) {
  unsigned u = __float_as_uint(x);
  u += 0x7FFFu + ((u >> 16) & 1u);
  return (u16)(u >> 16);
}
__device__ __forceinline__ float bf2f(u16 h) {
  return __uint_as_float(((unsigned)h) << 16);
}
__device__ __forceinline__ float sigf(float x) { return 1.0f / (1.0f + expf(-x)); }

// ---------------------------------------------------------------------------
// K0: build X split into bf16 hi/lo: X[m][c] = concat(enc[b], emb[gt[b][t]]),
// m = t*32 + b.  Feeds the bf16x3 MFMA preact GEMM.
// ---------------------------------------------------------------------------
__global__ __launch_bounds__(256) void build_x_split(const float* __restrict__ enc,
                                                     const int* __restrict__ gt,
                                                     const float* __restrict__ emb,
                                                     u16* __restrict__ Xhi,
                                                     u16* __restrict__ Xlo) {
  int m = blockIdx.x;                        // 0..2047
  int col = blockIdx.y * 256 + threadIdx.x;  // 0..1535
  int t = m >> 5, b = m & 31;
  float v;
  if (col < E_) {
    v = enc[b * E_ + col];
  } else {
    int gid = gt[b * T_ + t];
    v = emb[(size_t)gid * D_ + (col - E_)];
  }
  const u16 h = f2bf(v);
  Xhi[(size_t)m * ED_ + col] = h;
  Xlo[(size_t)m * ED_ + col] = f2bf(v - bf2f(h));
}

__global__ __launch_bounds__(256) void bias_sum_k(const float* __restrict__ a,
                                                  const float* __restrict__ b,
                                                  float* __restrict__ o) {
  int i = blockIdx.x * 256 + threadIdx.x;
  if (i < G4_) o[i] = a[i] + b[i];
}

// ---------------------------------------------------------------------------
// MFMA GEMM, bf16x3 emulated-fp32:
//   C = (Ahi+Alo)[M][K] * Bf[N][K]^T + bias[N]
// TRANS_OUT=0: C[m][n] (logits).  TRANS_OUT=1: C[t][n][b] with m = t*32+b
// (preact in the layout the persistent LSTM kernel consumes contiguously).
// 128x128 tile, BK=32, 4 waves (2x2), wave tile 64x64, mfma_f32_16x16x32_bf16,
// 3 MFMAs per fragment pair (drop lo*lo). LDS rows padded to 40 u16 (80 B).
// ---------------------------------------------------------------------------
template <int TRANS_OUT>
__global__ __launch_bounds__(256) void gemm_bf16x3(
    const u16* __restrict__ Ahi, const u16* __restrict__ Alo,
    const float* __restrict__ Bf, const float* __restrict__ bias,
    float* __restrict__ C, int M, int N, int K) {
  __shared__ __align__(16) u16 Ah_s[128 * 40];
  __shared__ __align__(16) u16 Al_s[128 * 40];
  __shared__ __align__(16) u16 Bh_s[128 * 40];
  __shared__ __align__(16) u16 Bl_s[128 * 40];

  const int tid = threadIdx.x;
  const int bn = blockIdx.x * 128;
  const int bm = blockIdx.y * 128;
  const int wave = tid >> 6, lane = tid & 63;
  const int wm = wave >> 1, wn = wave & 1;      // wave grid 2x2
  const int r16 = lane & 15, kj = lane >> 4;    // frag row/col, k-block

  const int ar = tid >> 1;
  const int ak = (tid & 1) * 16;
  const u16* gAh = Ahi + (size_t)(bm + ar) * K + ak;
  const u16* gAl = Alo + (size_t)(bm + ar) * K + ak;

  const int br = tid >> 3;         // 0..31
  const int bk = (tid & 7) * 4;    // float offset in k
  const float* gB = Bf + (size_t)(bn + br) * K + bk;

  f32x4 acc[4][4];
#pragma unroll
  for (int i = 0; i < 4; ++i)
#pragma unroll
    for (int j = 0; j < 4; ++j) acc[i][j] = (f32x4){0.f, 0.f, 0.f, 0.f};

  uint4 pa0 = *(const uint4*)(gAh);
  uint4 pa1 = *(const uint4*)(gAh + 8);
  uint4 pl0 = *(const uint4*)(gAl);
  uint4 pl1 = *(const uint4*)(gAl + 8);
  float4 pb[4];
#pragma unroll
  for (int p = 0; p < 4; ++p) pb[p] = *(const float4*)(gB + (size_t)(p * 32) * K);

  const int abase = (wm * 64 + r16) * 40 + kj * 8;
  const int bbase = (wn * 64 + r16) * 40 + kj * 8;

  for (int k0 = 0; k0 < K; k0 += 32) {
    union { u16 u[4]; uint2 v; } ph[4], pl[4];
#pragma unroll
    for (int p = 0; p < 4; ++p) {
      const float xe[4] = {pb[p].x, pb[p].y, pb[p].z, pb[p].w};
#pragma unroll
      for (int e = 0; e < 4; ++e) {
        const u16 h = f2bf(xe[e]);
        ph[p].u[e] = h;
        pl[p].u[e] = f2bf(xe[e] - bf2f(h));
      }
    }

    __syncthreads();
    *(uint4*)&Ah_s[ar * 40 + ak]     = pa0;
    *(uint4*)&Ah_s[ar * 40 + ak + 8] = pa1;
    *(uint4*)&Al_s[ar * 40 + ak]     = pl0;
    *(uint4*)&Al_s[ar * 40 + ak + 8] = pl1;
#pragma unroll
    for (int p = 0; p < 4; ++p) {
      *(uint2*)&Bh_s[(br + p * 32) * 40 + bk] = ph[p].v;
      *(uint2*)&Bl_s[(br + p * 32) * 40 + bk] = pl[p].v;
    }
    __syncthreads();

    if (k0 + 32 < K) {
      const int kn = k0 + 32;
      pa0 = *(const uint4*)(gAh + kn);
      pa1 = *(const uint4*)(gAh + kn + 8);
      pl0 = *(const uint4*)(gAl + kn);
      pl1 = *(const uint4*)(gAl + kn + 8);
#pragma unroll
      for (int p = 0; p < 4; ++p)
        pb[p] = *(const float4*)(gB + (size_t)(p * 32) * K + kn);
    }

    bf16x8 fah[4], fal[4];
#pragma unroll
    for (int i = 0; i < 4; ++i) {
      fah[i] = *(const bf16x8*)&Ah_s[abase + i * 640];
      fal[i] = *(const bf16x8*)&Al_s[abase + i * 640];
    }
#pragma unroll
    for (int j = 0; j < 4; ++j) {
      const bf16x8 fbh = *(const bf16x8*)&Bh_s[bbase + j * 640];
      const bf16x8 fbl = *(const bf16x8*)&Bl_s[bbase + j * 640];
#pragma unroll
      for (int i = 0; i < 4; ++i) {
        acc[i][j] = __builtin_amdgcn_mfma_f32_16x16x32_bf16(fah[i], fbh, acc[i][j], 0, 0, 0);
        acc[i][j] = __builtin_amdgcn_mfma_f32_16x16x32_bf16(fah[i], fbl, acc[i][j], 0, 0, 0);
        acc[i][j] = __builtin_amdgcn_mfma_f32_16x16x32_bf16(fal[i], fbh, acc[i][j], 0, 0, 0);
      }
    }
  }

  // C/D layout: col = lane&15, row = (lane>>4)*4 + reg (m89-verified)
#pragma unroll
  for (int j = 0; j < 4; ++j) {
    const int col = bn + wn * 64 + j * 16 + r16;
    const float bv = bias[col];
#pragma unroll
    for (int i = 0; i < 4; ++i) {
      const int row0 = bm + wm * 64 + i * 16 + kj * 4;
      if (TRANS_OUT) {
        // rows row0..row0+3 share t = row0>>5, b = (row0&31)+q consecutive
        float* p = C + ((size_t)(row0 >> 5) * G4_ + col) * B_ + (row0 & 31);
        *(float4*)p = make_float4(acc[i][j][0] + bv, acc[i][j][1] + bv,
                                  acc[i][j][2] + bv, acc[i][j][3] + bv);
      } else {
#pragma unroll
        for (int q = 0; q < 4; ++q)
          C[(size_t)(row0 + q) * N + col] = acc[i][j][q] + bv;
      }
    }
  }
}

// ---------------------------------------------------------------------------
// Persistent cooperative LSTM: all 64 steps, one grid.sync per step.
// 256 WGs x 256 threads. WG g owns h-slice {4g..4g+3} -> 16 W_hh rows
// (r = q*4+il -> j = q*1024 + 4g + il), staged ONCE in LDS as bf16 hi/lo.
// Gates via bf16x3 MFMA (A = h[t-1] hi/lo from global, k-split across 4
// waves, LDS reduce).  cx lives in registers (lanes 0..31 of wave 0, 4 each).
// h written as bf16 hi/lo -> Ahi/Alo[t] = next step's input AND final GEMM A.
// ---------------------------------------------------------------------------
__global__ __launch_bounds__(256) void lstm_loop(const float* __restrict__ W_hh,
                                                 const float* __restrict__ preT,
                                                 u16* __restrict__ Ahi,
                                                 u16* __restrict__ Alo) {
  cg::grid_group grid = cg::this_grid();
  const int g = blockIdx.x;        // 0..255
  const int tid = threadIdx.x;
  const int wave = tid >> 6, lane = tid & 63;
  const int r16 = lane & 15, kj = lane >> 4;

  __shared__ __align__(16) u16 Wh[16][1032];   // padded: stride 2064B, 2-way banks
  __shared__ __align__(16) u16 Wl[16][1032];
  __shared__ __align__(16) float red[4][2][64][4];  // per-wave partial accs
  __shared__ float pre_s[16][32];                   // preT slice [r][b]
  __shared__ float gsm[32][17];                     // gates [b][r], padded

  // stage W_hh slice once, split hi/lo
  for (int idx = tid; idx < 16 * 1024; idx += 256) {
    const int r = idx >> 10, k = idx & 1023;
    const int j = (r >> 2) * H_ + 4 * g + (r & 3);
    const float w = W_hh[(size_t)j * H_ + k];
    const u16 h = f2bf(w);
    Wh[r][k] = h;
    Wl[r][k] = f2bf(w - bf2f(h));
  }
  float creg[4] = {0.f, 0.f, 0.f, 0.f};   // cx for (b=tid, il=0..3), lanes<32
  __syncthreads();

  for (int t = 0; t < T_; ++t) {
    // prefetch preT[t] slice (512 floats), coalesced in b
    const int i1 = tid + 256;
    const int r0 = tid >> 5, b0 = tid & 31;
    const int r1 = i1 >> 5, b1 = i1 & 31;
    const float pv0 = preT[((size_t)t * G4_ + (r0 >> 2) * H_ + 4 * g + (r0 & 3)) * B_ + b0];
    const float pv1 = preT[((size_t)t * G4_ + (r1 >> 2) * H_ + 4 * g + (r1 & 3)) * B_ + b1];

    f32x4 acc[2];
    acc[0] = (f32x4){0.f, 0.f, 0.f, 0.f};
    acc[1] = (f32x4){0.f, 0.f, 0.f, 0.f};
    if (t > 0) {
      const u16* Ah = Ahi + (size_t)(t - 1) * B_ * H_;
      const u16* Al = Alo + (size_t)(t - 1) * B_ * H_;
      const int kbase = wave * 256;   // k-split across 4 waves
#pragma unroll
      for (int kt = 0; kt < 8; ++kt) {
        const int k = kbase + kt * 32 + kj * 8;
        const bf16x8 bh = *(const bf16x8*)&Wh[r16][k];
        const bf16x8 bl = *(const bf16x8*)&Wl[r16][k];
#pragma unroll
        for (int mi = 0; mi < 2; ++mi) {
          const bf16x8 ah = *(const bf16x8*)(Ah + (size_t)(mi * 16 + r16) * H_ + k);
          const bf16x8 al = *(const bf16x8*)(Al + (size_t)(mi * 16 + r16) * H_ + k);
          acc[mi] = __builtin_amdgcn_mfma_f32_16x16x32_bf16(ah, bh, acc[mi], 0, 0, 0);
          acc[mi] = __builtin_amdgcn_mfma_f32_16x16x32_bf16(ah, bl, acc[mi], 0, 0, 0);
          acc[mi] = __builtin_amdgcn_mfma_f32_16x16x32_bf16(al, bh, acc[mi], 0, 0, 0);
        }
      }
    }

    __syncthreads();   // prev iter's red/pre_s/gsm reads complete
    *(f32x4*)&red[wave][0][lane][0] = acc[0];
    *(f32x4*)&red[wave][1][lane][0] = acc[1];
    pre_s[r0][b0] = pv0;
    pre_s[r1][b1] = pv1;
    __syncthreads();

    // cross-wave reduce + add preact; gates -> gsm[b][r]
    for (int o = tid; o < 512; o += 256) {
      const int mi = o >> 8, l = (o >> 2) & 63, q = o & 3;
      const float s = red[0][mi][l][q] + red[1][mi][l][q] +
                      red[2][mi][l][q] + red[3][mi][l][q];
      const int b = mi * 16 + (l >> 4) * 4 + q;   // C/D row mapping
      const int r = l & 15;                        // C/D col mapping
      gsm[b][r] = s + pre_s[r][b];
    }
    __syncthreads();

    // cell update: 32 threads, 4 cells each
    if (tid < 32) {
      const int b = tid;
      ushort4 hh, hl;
      u16* hhp = &hh.x; u16* hlp = &hl.x;
#pragma unroll
      for (int il = 0; il < 4; ++il) {
        const float gi = gsm[b][il];
        const float gf = gsm[b][4 + il];
        const float gg = gsm[b][8 + il];
        const float go = gsm[b][12 + il];
        const float cn = sigf(gf) * creg[il] + sigf(gi) * tanhf(gg);
        const float hn = sigf(go) * tanhf(cn);
        creg[il] = cn;
        const u16 h16 = f2bf(hn);
        hhp[il] = h16;
        hlp[il] = f2bf(hn - bf2f(h16));
      }
      *(ushort4*)&Ahi[(size_t)(t * B_ + b) * H_ + 4 * g] = hh;
      *(ushort4*)&Alo[(size_t)(t * B_ + b) * H_ + 4 * g] = hl;
    }
    __threadfence();
    grid.sync();
  }
}

// ---------------------------------------------------------------------------
// K5: argmax over V per row m; predic[b][t] = argmax_v logits[m][v], first max.
// ---------------------------------------------------------------------------
__global__ __launch_bounds__(256) void argmax_rows(const float* __restrict__ logits,
                                                   float* __restrict__ predic) {
  const int m = blockIdx.x;  // 0..2047
  const float* row = logits + (size_t)m * V_;
  const int tid = threadIdx.x;
  float bv = -3.402823466e38f;
  int bi = V_;
  for (int v = tid; v < V_; v += 256) {
    float x = row[v];
    if (x > bv) { bv = x; bi = v; }   // ascending v => first-max kept
  }
  __shared__ float sv[256];
  __shared__ int si[256];
  sv[tid] = bv; si[tid] = bi;
  __syncthreads();
  for (int s = 128; s > 0; s >>= 1) {
    if (tid < s) {
      if (sv[tid + s] > sv[tid] ||
          (sv[tid + s] == sv[tid] && si[tid + s] < si[tid])) {
        sv[tid] = sv[tid + s];
        si[tid] = si[tid + s];
      }
    }
    __syncthreads();
  }
  if (tid == 0) {
    int t = m >> 5, b = m & 31;
    predic[b * T_ + t] = (float)si[0];
  }
}

// ---------------------------------------------------------------------------
extern "C" void kernel_launch(void* const* d_in, const int* in_sizes, int n_in,
                              void* d_out, int out_size, void* d_ws, size_t ws_size,
                              hipStream_t stream) {
  const float* enc  = (const float*)d_in[0];
  const int*   gt   = (const int*)d_in[1];
  const float* emb  = (const float*)d_in[2];
  const float* W_ih = (const float*)d_in[3];
  const float* W_hh = (const float*)d_in[4];
  const float* b_ih = (const float*)d_in[5];
  const float* b_hh = (const float*)d_in[6];
  const float* W_fc = (const float*)d_in[7];
  const float* b_fc = (const float*)d_in[8];
  // d_in[9]=ssprob=1, d_in[10]=is_train=1 -> teacher forcing always.

  float* out    = (float*)d_out;
  float* logits = out;                          // [2048][32000]
  float* predic = out + (size_t)M_ * V_;        // [32][64]

  // scratch inside d_out (dead before final GEMM overwrites it):
  u16*   Xhi    = (u16*)out;                    // [2048][1536] u16 (3 MB)
  u16*   Xlo    = Xhi + (size_t)M_ * ED_;       // next 3 MB (ends at float 1,572,864)
  float* preT   = out + 4194304;                // [64][4096][32] = 8,388,608 floats

  float* ws     = (float*)d_ws;
  float* bsum   = ws;                           // 4096
  u16*   Ahi    = (u16*)(ws + 4096);            // [2048][1024] u16 (4 MB)
  u16*   Alo    = Ahi + (size_t)M_ * H_;        // 4 MB

  build_x_split<<<dim3(M_, 6), 256, 0, stream>>>(enc, gt, emb, Xhi, Xlo);
  bias_sum_k<<<16, 256, 0, stream>>>(b_ih, b_hh, bsum);

  // preT[t][j][b] = X @ W_ih^T + (b_ih + b_hh)   (bf16x3 MFMA, transposed out)
  gemm_bf16x3<1><<<dim3(G4_ / 128, M_ / 128), 256, 0, stream>>>(
      Xhi, Xlo, W_ih, bsum, preT, M_, G4_, ED_);

  // all 64 recurrent steps in one cooperative kernel
  {
    void* args[] = {(void*)&W_hh, (void*)&preT, (void*)&Ahi, (void*)&Alo};
    hipLaunchCooperativeKernel((void*)lstm_loop, dim3(256), dim3(256), args, 0,
                               stream);
  }

  // logits = (Ahi+Alo) @ W_fc^T + b_fc   (bf16x3 MFMA)
  gemm_bf16x3<0><<<dim3(V_ / 128, M_ / 128), 256, 0, stream>>>(
      Ahi, Alo, W_fc, b_fc, logits, M_, V_, H_);

  argmax_rows<<<M_, 256, 0, stream>>>(logits, predic);
}

// Round 3
// 2448.254 us; speedup vs baseline: 1.8862x; 1.8862x over previous
//
#include <hip/hip_runtime.h>
#include <math.h>

#define B_ 32
#define T_ 64
#define V_ 32000
#define D_ 512
#define E_ 1024
#define H_ 1024
#define G4_ 4096   // 4*H
#define ED_ 1536   // E + D
#define M_ 2048    // T*B
#define NB_ 256    // persistent-kernel block count

typedef unsigned short u16;

using bf16x8 = __attribute__((ext_vector_type(8))) short;
using f32x4  = __attribute__((ext_vector_type(4))) float;

// fp32 -> bf16 (RNE) and back, bit-level (values here are finite/normal)
__device__ __forceinline__ u16 f2bf(float x) {
  unsigned u = __float_as_uint(x);
  u += 0x7FFFu + ((u >> 16) & 1u);
  return (u16)(u >> 16);
}
__device__ __forceinline__ float bf2f(u16 h) {
  return __uint_as_float(((unsigned)h) << 16);
}
__device__ __forceinline__ float sigf(float x) { return 1.0f / (1.0f + expf(-x)); }

// ---------------------------------------------------------------------------
// K0: build X split into bf16 hi/lo: X[m][c] = concat(enc[b], emb[gt[b][t]]),
// m = t*32 + b.  Feeds the bf16x3 MFMA preact GEMM.
// ---------------------------------------------------------------------------
__global__ __launch_bounds__(256) void build_x_split(const float* __restrict__ enc,
                                                     const int* __restrict__ gt,
                                                     const float* __restrict__ emb,
                                                     u16* __restrict__ Xhi,
                                                     u16* __restrict__ Xlo) {
  int m = blockIdx.x;                        // 0..2047
  int col = blockIdx.y * 256 + threadIdx.x;  // 0..1535
  int t = m >> 5, b = m & 31;
  float v;
  if (col < E_) {
    v = enc[b * E_ + col];
  } else {
    int gid = gt[b * T_ + t];
    v = emb[(size_t)gid * D_ + (col - E_)];
  }
  const u16 h = f2bf(v);
  Xhi[(size_t)m * ED_ + col] = h;
  Xlo[(size_t)m * ED_ + col] = f2bf(v - bf2f(h));
}

__global__ __launch_bounds__(256) void bias_sum_k(const float* __restrict__ a,
                                                  const float* __restrict__ b,
                                                  float* __restrict__ o) {
  int i = blockIdx.x * 256 + threadIdx.x;
  if (i < G4_) o[i] = a[i] + b[i];
}

// ---------------------------------------------------------------------------
// MFMA GEMM, bf16x3 emulated-fp32:
//   C = (Ahi+Alo)[M][K] * Bf[N][K]^T + bias[N]
// TRANS_OUT=0: C[m][n] (logits).  TRANS_OUT=1: C[t][n][b] with m = t*32+b.
// 128x128 tile, BK=32, 4 waves (2x2), wave tile 64x64, mfma_f32_16x16x32_bf16,
// 3 MFMAs per fragment pair (drop lo*lo). LDS rows padded to 40 u16 (80 B).
// ---------------------------------------------------------------------------
template <int TRANS_OUT>
__global__ __launch_bounds__(256) void gemm_bf16x3(
    const u16* __restrict__ Ahi, const u16* __restrict__ Alo,
    const float* __restrict__ Bf, const float* __restrict__ bias,
    float* __restrict__ C, int M, int N, int K) {
  __shared__ __align__(16) u16 Ah_s[128 * 40];
  __shared__ __align__(16) u16 Al_s[128 * 40];
  __shared__ __align__(16) u16 Bh_s[128 * 40];
  __shared__ __align__(16) u16 Bl_s[128 * 40];

  const int tid = threadIdx.x;
  const int bn = blockIdx.x * 128;
  const int bm = blockIdx.y * 128;
  const int wave = tid >> 6, lane = tid & 63;
  const int wm = wave >> 1, wn = wave & 1;      // wave grid 2x2
  const int r16 = lane & 15, kj = lane >> 4;    // frag row/col, k-block

  const int ar = tid >> 1;
  const int ak = (tid & 1) * 16;
  const u16* gAh = Ahi + (size_t)(bm + ar) * K + ak;
  const u16* gAl = Alo + (size_t)(bm + ar) * K + ak;

  const int br = tid >> 3;         // 0..31
  const int bk = (tid & 7) * 4;    // float offset in k
  const float* gB = Bf + (size_t)(bn + br) * K + bk;

  f32x4 acc[4][4];
#pragma unroll
  for (int i = 0; i < 4; ++i)
#pragma unroll
    for (int j = 0; j < 4; ++j) acc[i][j] = (f32x4){0.f, 0.f, 0.f, 0.f};

  uint4 pa0 = *(const uint4*)(gAh);
  uint4 pa1 = *(const uint4*)(gAh + 8);
  uint4 pl0 = *(const uint4*)(gAl);
  uint4 pl1 = *(const uint4*)(gAl + 8);
  float4 pb[4];
#pragma unroll
  for (int p = 0; p < 4; ++p) pb[p] = *(const float4*)(gB + (size_t)(p * 32) * K);

  const int abase = (wm * 64 + r16) * 40 + kj * 8;
  const int bbase = (wn * 64 + r16) * 40 + kj * 8;

  for (int k0 = 0; k0 < K; k0 += 32) {
    union { u16 u[4]; uint2 v; } ph[4], pl[4];
#pragma unroll
    for (int p = 0; p < 4; ++p) {
      const float xe[4] = {pb[p].x, pb[p].y, pb[p].z, pb[p].w};
#pragma unroll
      for (int e = 0; e < 4; ++e) {
        const u16 h = f2bf(xe[e]);
        ph[p].u[e] = h;
        pl[p].u[e] = f2bf(xe[e] - bf2f(h));
      }
    }

    __syncthreads();
    *(uint4*)&Ah_s[ar * 40 + ak]     = pa0;
    *(uint4*)&Ah_s[ar * 40 + ak + 8] = pa1;
    *(uint4*)&Al_s[ar * 40 + ak]     = pl0;
    *(uint4*)&Al_s[ar * 40 + ak + 8] = pl1;
#pragma unroll
    for (int p = 0; p < 4; ++p) {
      *(uint2*)&Bh_s[(br + p * 32) * 40 + bk] = ph[p].v;
      *(uint2*)&Bl_s[(br + p * 32) * 40 + bk] = pl[p].v;
    }
    __syncthreads();

    if (k0 + 32 < K) {
      const int kn = k0 + 32;
      pa0 = *(const uint4*)(gAh + kn);
      pa1 = *(const uint4*)(gAh + kn + 8);
      pl0 = *(const uint4*)(gAl + kn);
      pl1 = *(const uint4*)(gAl + kn + 8);
#pragma unroll
      for (int p = 0; p < 4; ++p)
        pb[p] = *(const float4*)(gB + (size_t)(p * 32) * K + kn);
    }

    bf16x8 fah[4], fal[4];
#pragma unroll
    for (int i = 0; i < 4; ++i) {
      fah[i] = *(const bf16x8*)&Ah_s[abase + i * 640];
      fal[i] = *(const bf16x8*)&Al_s[abase + i * 640];
    }
#pragma unroll
    for (int j = 0; j < 4; ++j) {
      const bf16x8 fbh = *(const bf16x8*)&Bh_s[bbase + j * 640];
      const bf16x8 fbl = *(const bf16x8*)&Bl_s[bbase + j * 640];
#pragma unroll
      for (int i = 0; i < 4; ++i) {
        acc[i][j] = __builtin_amdgcn_mfma_f32_16x16x32_bf16(fah[i], fbh, acc[i][j], 0, 0, 0);
        acc[i][j] = __builtin_amdgcn_mfma_f32_16x16x32_bf16(fah[i], fbl, acc[i][j], 0, 0, 0);
        acc[i][j] = __builtin_amdgcn_mfma_f32_16x16x32_bf16(fal[i], fbh, acc[i][j], 0, 0, 0);
      }
    }
  }

  // C/D layout: col = lane&15, row = (lane>>4)*4 + reg (m89-verified)
#pragma unroll
  for (int j = 0; j < 4; ++j) {
    const int col = bn + wn * 64 + j * 16 + r16;
    const float bv = bias[col];
#pragma unroll
    for (int i = 0; i < 4; ++i) {
      const int row0 = bm + wm * 64 + i * 16 + kj * 4;
      if (TRANS_OUT) {
        float* p = C + ((size_t)(row0 >> 5) * G4_ + col) * B_ + (row0 & 31);
        *(float4*)p = make_float4(acc[i][j][0] + bv, acc[i][j][1] + bv,
                                  acc[i][j][2] + bv, acc[i][j][3] + bv);
      } else {
#pragma unroll
        for (int q = 0; q < 4; ++q)
          C[(size_t)(row0 + q) * N + col] = acc[i][j][q] + bv;
      }
    }
  }
}

// ---------------------------------------------------------------------------
// Persistent LSTM, all 64 steps. 256 WGs x 256 threads, NORMAL launch.
// Per-step device barrier = hand-rolled flag barrier (cg::grid.sync measured
// ~56 us/step -- s_sleep backoff; this spin barrier targets ~2-4 us):
//   writer side: __syncthreads() drains h-stores (vmcnt0@barrier), then
//     tid0 agent-RELEASE atomic store of flags[t][bid] (emits L2 writeback ->
//     h published to coherence point / MALL).
//   waiter side: wave0 spin-polls 256 flags (relaxed agent atomic loads,
//     4/lane), __syncthreads(), then agent ACQUIRE fence by all threads
//     (L2 inv) before reading h[t]. Per-t flag array => no reuse race.
// WG g owns h-slice {4g..4g+3} -> 16 W_hh rows in LDS as bf16 hi/lo (staged
// once). Gates via bf16x3 MFMA, k-split across 4 waves, LDS reduce. cx in
// registers (lanes 0..31). h written as bf16 hi/lo -> Ahi/Alo[t].
// ---------------------------------------------------------------------------
__global__ __launch_bounds__(256) void lstm_loop(const float* __restrict__ W_hh,
                                                 const float* __restrict__ preT,
                                                 u16* __restrict__ Ahi,
                                                 u16* __restrict__ Alo,
                                                 int* __restrict__ flags) {
  const int g = blockIdx.x;        // 0..255
  const int tid = threadIdx.x;
  const int wave = tid >> 6, lane = tid & 63;
  const int r16 = lane & 15, kj = lane >> 4;

  __shared__ __align__(16) u16 Wh[16][1032];   // padded: stride 2064B
  __shared__ __align__(16) u16 Wl[16][1032];
  __shared__ __align__(16) float red[4][2][64][4];  // per-wave partial accs
  __shared__ float pre_s[16][32];                   // preT slice [r][b]
  __shared__ float gsm[32][17];                     // gates [b][r], padded

  // stage W_hh slice once, split hi/lo
  for (int idx = tid; idx < 16 * 1024; idx += 256) {
    const int r = idx >> 10, k = idx & 1023;
    const int j = (r >> 2) * H_ + 4 * g + (r & 3);
    const float w = W_hh[(size_t)j * H_ + k];
    const u16 h = f2bf(w);
    Wh[r][k] = h;
    Wl[r][k] = f2bf(w - bf2f(h));
  }
  float creg[4] = {0.f, 0.f, 0.f, 0.f};   // cx for (b=tid, il=0..3), lanes<32
  __syncthreads();

  for (int t = 0; t < T_; ++t) {
    // prefetch preT[t] slice (512 floats), coalesced in b
    const int i1 = tid + 256;
    const int r0 = tid >> 5, b0 = tid & 31;
    const int r1 = i1 >> 5, b1 = i1 & 31;
    const float pv0 = preT[((size_t)t * G4_ + (r0 >> 2) * H_ + 4 * g + (r0 & 3)) * B_ + b0];
    const float pv1 = preT[((size_t)t * G4_ + (r1 >> 2) * H_ + 4 * g + (r1 & 3)) * B_ + b1];

    f32x4 acc[2];
    acc[0] = (f32x4){0.f, 0.f, 0.f, 0.f};
    acc[1] = (f32x4){0.f, 0.f, 0.f, 0.f};
    if (t > 0) {
      const u16* Ah = Ahi + (size_t)(t - 1) * B_ * H_;
      const u16* Al = Alo + (size_t)(t - 1) * B_ * H_;
      const int kbase = wave * 256;   // k-split across 4 waves
#pragma unroll
      for (int kt = 0; kt < 8; ++kt) {
        const int k = kbase + kt * 32 + kj * 8;
        const bf16x8 bh = *(const bf16x8*)&Wh[r16][k];
        const bf16x8 bl = *(const bf16x8*)&Wl[r16][k];
#pragma unroll
        for (int mi = 0; mi < 2; ++mi) {
          const bf16x8 ah = *(const bf16x8*)(Ah + (size_t)(mi * 16 + r16) * H_ + k);
          const bf16x8 al = *(const bf16x8*)(Al + (size_t)(mi * 16 + r16) * H_ + k);
          acc[mi] = __builtin_amdgcn_mfma_f32_16x16x32_bf16(ah, bh, acc[mi], 0, 0, 0);
          acc[mi] = __builtin_amdgcn_mfma_f32_16x16x32_bf16(ah, bl, acc[mi], 0, 0, 0);
          acc[mi] = __builtin_amdgcn_mfma_f32_16x16x32_bf16(al, bh, acc[mi], 0, 0, 0);
        }
      }
    }

    __syncthreads();   // prev iter's red/pre_s/gsm reads complete
    *(f32x4*)&red[wave][0][lane][0] = acc[0];
    *(f32x4*)&red[wave][1][lane][0] = acc[1];
    pre_s[r0][b0] = pv0;
    pre_s[r1][b1] = pv1;
    __syncthreads();

    // cross-wave reduce + add preact; gates -> gsm[b][r]
    for (int o = tid; o < 512; o += 256) {
      const int mi = o >> 8, l = (o >> 2) & 63, q = o & 3;
      const float s = red[0][mi][l][q] + red[1][mi][l][q] +
                      red[2][mi][l][q] + red[3][mi][l][q];
      const int b = mi * 16 + (l >> 4) * 4 + q;   // C/D row mapping
      const int r = l & 15;                        // C/D col mapping
      gsm[b][r] = s + pre_s[r][b];
    }
    __syncthreads();

    // cell update: 32 threads, 4 cells each
    if (tid < 32) {
      const int b = tid;
      ushort4 hh, hl;
      u16* hhp = &hh.x; u16* hlp = &hl.x;
#pragma unroll
      for (int il = 0; il < 4; ++il) {
        const float gi = gsm[b][il];
        const float gf = gsm[b][4 + il];
        const float gg = gsm[b][8 + il];
        const float go = gsm[b][12 + il];
        const float cn = sigf(gf) * creg[il] + sigf(gi) * tanhf(gg);
        const float hn = sigf(go) * tanhf(cn);
        creg[il] = cn;
        const u16 h16 = f2bf(hn);
        hhp[il] = h16;
        hlp[il] = f2bf(hn - bf2f(h16));
      }
      *(ushort4*)&Ahi[(size_t)(t * B_ + b) * H_ + 4 * g] = hh;
      *(ushort4*)&Alo[(size_t)(t * B_ + b) * H_ + 4 * g] = hl;
    }

    // ---- device barrier for step t ----
    __syncthreads();   // h stores drained (vmcnt0 before s_barrier)
    if (tid == 0)
      __hip_atomic_store(&flags[t * NB_ + g], 1, __ATOMIC_RELEASE,
                         __HIP_MEMORY_SCOPE_AGENT);
    if (wave == 0) {
      const int* fp = flags + t * NB_ + lane * 4;
      for (;;) {
        const int a = __hip_atomic_load(fp + 0, __ATOMIC_RELAXED, __HIP_MEMORY_SCOPE_AGENT);
        const int b2 = __hip_atomic_load(fp + 1, __ATOMIC_RELAXED, __HIP_MEMORY_SCOPE_AGENT);
        const int c = __hip_atomic_load(fp + 2, __ATOMIC_RELAXED, __HIP_MEMORY_SCOPE_AGENT);
        const int d = __hip_atomic_load(fp + 3, __ATOMIC_RELAXED, __HIP_MEMORY_SCOPE_AGENT);
        if (__all((a & b2 & c & d) != 0)) break;
      }
    }
    __syncthreads();   // waiters released only after wave0 sees all flags
    __builtin_amdgcn_fence(__ATOMIC_ACQUIRE, "agent");  // L2 inv before h[t] reads
  }
}

// ---------------------------------------------------------------------------
// K5: argmax over V per row m; predic[b][t] = argmax_v logits[m][v], first max.
// ---------------------------------------------------------------------------
__global__ __launch_bounds__(256) void argmax_rows(const float* __restrict__ logits,
                                                   float* __restrict__ predic) {
  const int m = blockIdx.x;  // 0..2047
  const float* row = logits + (size_t)m * V_;
  const int tid = threadIdx.x;
  float bv = -3.402823466e38f;
  int bi = V_;
  for (int v = tid; v < V_; v += 256) {
    float x = row[v];
    if (x > bv) { bv = x; bi = v; }   // ascending v => first-max kept
  }
  __shared__ float sv[256];
  __shared__ int si[256];
  sv[tid] = bv; si[tid] = bi;
  __syncthreads();
  for (int s = 128; s > 0; s >>= 1) {
    if (tid < s) {
      if (sv[tid + s] > sv[tid] ||
          (sv[tid + s] == sv[tid] && si[tid + s] < si[tid])) {
        sv[tid] = sv[tid + s];
        si[tid] = si[tid + s];
      }
    }
    __syncthreads();
  }
  if (tid == 0) {
    int t = m >> 5, b = m & 31;
    predic[b * T_ + t] = (float)si[0];
  }
}

// ---------------------------------------------------------------------------
extern "C" void kernel_launch(void* const* d_in, const int* in_sizes, int n_in,
                              void* d_out, int out_size, void* d_ws, size_t ws_size,
                              hipStream_t stream) {
  const float* enc  = (const float*)d_in[0];
  const int*   gt   = (const int*)d_in[1];
  const float* emb  = (const float*)d_in[2];
  const float* W_ih = (const float*)d_in[3];
  const float* W_hh = (const float*)d_in[4];
  const float* b_ih = (const float*)d_in[5];
  const float* b_hh = (const float*)d_in[6];
  const float* W_fc = (const float*)d_in[7];
  const float* b_fc = (const float*)d_in[8];
  // d_in[9]=ssprob=1, d_in[10]=is_train=1 -> teacher forcing always.

  float* out    = (float*)d_out;
  float* logits = out;                          // [2048][32000]
  float* predic = out + (size_t)M_ * V_;        // [32][64]

  // scratch inside d_out (dead before final GEMM overwrites it):
  u16*   Xhi    = (u16*)out;                    // [2048][1536] u16 (3 MB)
  u16*   Xlo    = Xhi + (size_t)M_ * ED_;       // next 3 MB
  float* preT   = out + 4194304;                // [64][4096][32] = 8,388,608 floats

  float* ws     = (float*)d_ws;
  float* bsum   = ws;                           // 4096
  u16*   Ahi    = (u16*)(ws + 4096);            // [2048][1024] u16 (4 MB)
  u16*   Alo    = Ahi + (size_t)M_ * H_;        // 4 MB
  int*   flags  = (int*)(Alo + (size_t)M_ * H_); // [64][256] = 64 KB

  hipMemsetAsync(flags, 0, T_ * NB_ * sizeof(int), stream);

  build_x_split<<<dim3(M_, 6), 256, 0, stream>>>(enc, gt, emb, Xhi, Xlo);
  bias_sum_k<<<16, 256, 0, stream>>>(b_ih, b_hh, bsum);

  // preT[t][j][b] = X @ W_ih^T + (b_ih + b_hh)   (bf16x3 MFMA, transposed out)
  gemm_bf16x3<1><<<dim3(G4_ / 128, M_ / 128), 256, 0, stream>>>(
      Xhi, Xlo, W_ih, bsum, preT, M_, G4_, ED_);

  // all 64 recurrent steps in one persistent kernel (flag barrier per step)
  lstm_loop<<<NB_, 256, 0, stream>>>(W_hh, preT, Ahi, Alo, flags);

  // logits = (Ahi+Alo) @ W_fc^T + b_fc   (bf16x3 MFMA)
  gemm_bf16x3<0><<<dim3(V_ / 128, M_ / 128), 256, 0, stream>>>(
      Ahi, Alo, W_fc, b_fc, logits, M_, V_, H_);

  argmax_rows<<<M_, 256, 0, stream>>>(logits, predic);
}

// Round 4
// 1744.108 us; speedup vs baseline: 2.6478x; 1.4037x over previous
//
#include <hip/hip_runtime.h>
#include <math.h>

#define B_ 32
#define T_ 64
#define V_ 32000
#define D_ 512
#define E_ 1024
#define H_ 1024
#define G4_ 4096   // 4*H
#define ED_ 1536   // E + D
#define M_ 2048    // T*B
#define NB_ 512    // persistent blocks: 2 halves x 256
#define NG_ 256    // blocks per barrier group

typedef unsigned short u16;

using bf16x8 = __attribute__((ext_vector_type(8))) short;
using f32x4  = __attribute__((ext_vector_type(4))) float;

// fp32 -> bf16 (RNE) and back, bit-level (values here are finite/normal)
__device__ __forceinline__ u16 f2bf(float x) {
  unsigned u = __float_as_uint(x);
  u += 0x7FFFu + ((u >> 16) & 1u);
  return (u16)(u >> 16);
}
__device__ __forceinline__ float bf2f(u16 h) {
  return __uint_as_float(((unsigned)h) << 16);
}
__device__ __forceinline__ float sigf(float x) { return 1.0f / (1.0f + expf(-x)); }

// MALL-direct 8B store (bypass L1/L2 so no wbl2/inv fences are needed)
__device__ __forceinline__ void store8_mall(void* p, uint2 v) {
  asm volatile("global_store_dwordx2 %0, %1, off sc0 sc1 nt"
               :: "v"(p), "v"(v) : "memory");
}

// ---------------------------------------------------------------------------
// K0: build X split into bf16 hi/lo: X[m][c] = concat(enc[b], emb[gt[b][t]]),
// m = t*32 + b.  Feeds the bf16x3 MFMA preact GEMM.
// ---------------------------------------------------------------------------
__global__ __launch_bounds__(256) void build_x_split(const float* __restrict__ enc,
                                                     const int* __restrict__ gt,
                                                     const float* __restrict__ emb,
                                                     u16* __restrict__ Xhi,
                                                     u16* __restrict__ Xlo) {
  int m = blockIdx.x;                        // 0..2047
  int col = blockIdx.y * 256 + threadIdx.x;  // 0..1535
  int t = m >> 5, b = m & 31;
  float v;
  if (col < E_) {
    v = enc[b * E_ + col];
  } else {
    int gid = gt[b * T_ + t];
    v = emb[(size_t)gid * D_ + (col - E_)];
  }
  const u16 h = f2bf(v);
  Xhi[(size_t)m * ED_ + col] = h;
  Xlo[(size_t)m * ED_ + col] = f2bf(v - bf2f(h));
}

__global__ __launch_bounds__(256) void bias_sum_k(const float* __restrict__ a,
                                                  const float* __restrict__ b,
                                                  float* __restrict__ o) {
  int i = blockIdx.x * 256 + threadIdx.x;
  if (i < G4_) o[i] = a[i] + b[i];
}

// ---------------------------------------------------------------------------
// MFMA GEMM, bf16x3 emulated-fp32:
//   C = (Ahi+Alo)[M][K] * Bf[N][K]^T + bias[N]
// TRANS_OUT=0: C[m][n] (logits).  TRANS_OUT=1: C[t][n][b] with m = t*32+b.
// 128x128 tile, BK=32, 4 waves (2x2), wave tile 64x64, mfma_f32_16x16x32_bf16,
// 3 MFMAs per fragment pair (drop lo*lo). LDS rows padded to 40 u16 (80 B).
// ---------------------------------------------------------------------------
template <int TRANS_OUT>
__global__ __launch_bounds__(256) void gemm_bf16x3(
    const u16* __restrict__ Ahi, const u16* __restrict__ Alo,
    const float* __restrict__ Bf, const float* __restrict__ bias,
    float* __restrict__ C, int M, int N, int K) {
  __shared__ __align__(16) u16 Ah_s[128 * 40];
  __shared__ __align__(16) u16 Al_s[128 * 40];
  __shared__ __align__(16) u16 Bh_s[128 * 40];
  __shared__ __align__(16) u16 Bl_s[128 * 40];

  const int tid = threadIdx.x;
  const int bn = blockIdx.x * 128;
  const int bm = blockIdx.y * 128;
  const int wave = tid >> 6, lane = tid & 63;
  const int wm = wave >> 1, wn = wave & 1;      // wave grid 2x2
  const int r16 = lane & 15, kj = lane >> 4;    // frag row/col, k-block

  const int ar = tid >> 1;
  const int ak = (tid & 1) * 16;
  const u16* gAh = Ahi + (size_t)(bm + ar) * K + ak;
  const u16* gAl = Alo + (size_t)(bm + ar) * K + ak;

  const int br = tid >> 3;         // 0..31
  const int bk = (tid & 7) * 4;    // float offset in k
  const float* gB = Bf + (size_t)(bn + br) * K + bk;

  f32x4 acc[4][4];
#pragma unroll
  for (int i = 0; i < 4; ++i)
#pragma unroll
    for (int j = 0; j < 4; ++j) acc[i][j] = (f32x4){0.f, 0.f, 0.f, 0.f};

  uint4 pa0 = *(const uint4*)(gAh);
  uint4 pa1 = *(const uint4*)(gAh + 8);
  uint4 pl0 = *(const uint4*)(gAl);
  uint4 pl1 = *(const uint4*)(gAl + 8);
  float4 pb[4];
#pragma unroll
  for (int p = 0; p < 4; ++p) pb[p] = *(const float4*)(gB + (size_t)(p * 32) * K);

  const int abase = (wm * 64 + r16) * 40 + kj * 8;
  const int bbase = (wn * 64 + r16) * 40 + kj * 8;

  for (int k0 = 0; k0 < K; k0 += 32) {
    union { u16 u[4]; uint2 v; } ph[4], pl[4];
#pragma unroll
    for (int p = 0; p < 4; ++p) {
      const float xe[4] = {pb[p].x, pb[p].y, pb[p].z, pb[p].w};
#pragma unroll
      for (int e = 0; e < 4; ++e) {
        const u16 h = f2bf(xe[e]);
        ph[p].u[e] = h;
        pl[p].u[e] = f2bf(xe[e] - bf2f(h));
      }
    }

    __syncthreads();
    *(uint4*)&Ah_s[ar * 40 + ak]     = pa0;
    *(uint4*)&Ah_s[ar * 40 + ak + 8] = pa1;
    *(uint4*)&Al_s[ar * 40 + ak]     = pl0;
    *(uint4*)&Al_s[ar * 40 + ak + 8] = pl1;
#pragma unroll
    for (int p = 0; p < 4; ++p) {
      *(uint2*)&Bh_s[(br + p * 32) * 40 + bk] = ph[p].v;
      *(uint2*)&Bl_s[(br + p * 32) * 40 + bk] = pl[p].v;
    }
    __syncthreads();

    if (k0 + 32 < K) {
      const int kn = k0 + 32;
      pa0 = *(const uint4*)(gAh + kn);
      pa1 = *(const uint4*)(gAh + kn + 8);
      pl0 = *(const uint4*)(gAl + kn);
      pl1 = *(const uint4*)(gAl + kn + 8);
#pragma unroll
      for (int p = 0; p < 4; ++p)
        pb[p] = *(const float4*)(gB + (size_t)(p * 32) * K + kn);
    }

    bf16x8 fah[4], fal[4];
#pragma unroll
    for (int i = 0; i < 4; ++i) {
      fah[i] = *(const bf16x8*)&Ah_s[abase + i * 640];
      fal[i] = *(const bf16x8*)&Al_s[abase + i * 640];
    }
#pragma unroll
    for (int j = 0; j < 4; ++j) {
      const bf16x8 fbh = *(const bf16x8*)&Bh_s[bbase + j * 640];
      const bf16x8 fbl = *(const bf16x8*)&Bl_s[bbase + j * 640];
#pragma unroll
      for (int i = 0; i < 4; ++i) {
        acc[i][j] = __builtin_amdgcn_mfma_f32_16x16x32_bf16(fah[i], fbh, acc[i][j], 0, 0, 0);
        acc[i][j] = __builtin_amdgcn_mfma_f32_16x16x32_bf16(fah[i], fbl, acc[i][j], 0, 0, 0);
        acc[i][j] = __builtin_amdgcn_mfma_f32_16x16x32_bf16(fal[i], fbh, acc[i][j], 0, 0, 0);
      }
    }
  }

  // C/D layout: col = lane&15, row = (lane>>4)*4 + reg (m89-verified)
#pragma unroll
  for (int j = 0; j < 4; ++j) {
    const int col = bn + wn * 64 + j * 16 + r16;
    const float bv = bias[col];
#pragma unroll
    for (int i = 0; i < 4; ++i) {
      const int row0 = bm + wm * 64 + i * 16 + kj * 4;
      if (TRANS_OUT) {
        float* p = C + ((size_t)(row0 >> 5) * G4_ + col) * B_ + (row0 & 31);
        *(float4*)p = make_float4(acc[i][j][0] + bv, acc[i][j][1] + bv,
                                  acc[i][j][2] + bv, acc[i][j][3] + bv);
      } else {
#pragma unroll
        for (int q = 0; q < 4; ++q)
          C[(size_t)(row0 + q) * N + col] = acc[i][j][q] + bv;
      }
    }
  }
}

// ---------------------------------------------------------------------------
// Persistent LSTM, all 64 steps. 512 WGs x 256 threads (2 blocks/CU).
// Batch split: half = bid>>8 owns b-range [half*16, half*16+16) -- the two
// halves are INDEPENDENT recurrences with separate 256-block flag barriers,
// so their phases slide and hide each other's spin on the shared CU.
// Fence-free protocol:
//   - h written with MALL-direct stores (sc0 sc1 nt) + s_waitcnt vmcnt(0):
//     nothing dirty in L2 -> no wbl2 release fence needed.
//   - step flag = RELAXED agent atomic store (ordering via vmcnt + barrier).
//   - readers use normal cached loads: per-step h addresses are fresh
//     (written once, read once) so no cache can hold a stale copy -> no
//     acquire/L2-inv fence needed.
// WG g owns j-slice {4g..4g+3} -> 16 W_hh rows in LDS bf16 hi/lo (staged
// once, 66 KB). Gates via bf16x3 MFMA, k-split across 4 waves, LDS reduce.
// cx in registers (lanes 0..15). preT(t+1) prefetched under the spin.
// ---------------------------------------------------------------------------
__global__ __launch_bounds__(256) void lstm_loop(const float* __restrict__ W_hh,
                                                 const float* __restrict__ preT,
                                                 u16* __restrict__ Ahi,
                                                 u16* __restrict__ Alo,
                                                 int* __restrict__ flags) {
  const int g = blockIdx.x & 255;     // j-slice owner
  const int half = blockIdx.x >> 8;   // batch half
  const int tid = threadIdx.x;
  const int wave = tid >> 6, lane = tid & 63;
  const int r16 = lane & 15, kj = lane >> 4;

  __shared__ __align__(16) u16 Wh[16][1032];   // padded: stride 2064B
  __shared__ __align__(16) u16 Wl[16][1032];
  __shared__ __align__(16) float red[4][64][4];  // per-wave partial accs
  __shared__ float pre_s[16][16];                // preT slice [r][b-local]
  __shared__ float gsm[16][17];                  // gates [b-local][r], padded

  // stage W_hh slice once, split hi/lo
  for (int idx = tid; idx < 16 * 1024; idx += 256) {
    const int r = idx >> 10, k = idx & 1023;
    const int j = (r >> 2) * H_ + 4 * g + (r & 3);
    const float w = W_hh[(size_t)j * H_ + k];
    const u16 h = f2bf(w);
    Wh[r][k] = h;
    Wl[r][k] = f2bf(w - bf2f(h));
  }
  float creg[4] = {0.f, 0.f, 0.f, 0.f};   // cx for (b-local=lane, il=0..3), lanes<16

  // preT prefetch for t=0: 256 elems, 1/thread: r = tid>>4, b-local = tid&15
  const int pr = tid >> 4, pbl = tid & 15;
  const size_t pre_base = ((size_t)(pr >> 2) * H_ + 4 * g + (pr & 3)) * B_ +
                          half * 16 + pbl;
  float pv = preT[pre_base];

  __syncthreads();

  for (int t = 0; t < T_; ++t) {
    f32x4 acc = (f32x4){0.f, 0.f, 0.f, 0.f};
    if (t > 0) {
      const u16* Ah = Ahi + (size_t)(t - 1) * B_ * H_ + (size_t)(half * 16 + r16) * H_;
      const u16* Al = Alo + (size_t)(t - 1) * B_ * H_ + (size_t)(half * 16 + r16) * H_;
      const int kbase = wave * 256;   // k-split across 4 waves
#pragma unroll
      for (int kt = 0; kt < 8; ++kt) {
        const int k = kbase + kt * 32 + kj * 8;
        const bf16x8 bh = *(const bf16x8*)&Wh[r16][k];
        const bf16x8 bl = *(const bf16x8*)&Wl[r16][k];
        const bf16x8 ah = *(const bf16x8*)(Ah + k);
        const bf16x8 al = *(const bf16x8*)(Al + k);
        acc = __builtin_amdgcn_mfma_f32_16x16x32_bf16(ah, bh, acc, 0, 0, 0);
        acc = __builtin_amdgcn_mfma_f32_16x16x32_bf16(ah, bl, acc, 0, 0, 0);
        acc = __builtin_amdgcn_mfma_f32_16x16x32_bf16(al, bh, acc, 0, 0, 0);
      }
    }

    __syncthreads();   // prev iter's red/pre_s/gsm reads complete
    *(f32x4*)&red[wave][lane][0] = acc;
    pre_s[pr][pbl] = pv;
    __syncthreads();

    // cross-wave reduce + add preact; gates -> gsm[b-local][r]
    {
      const int l = tid >> 2, q = tid & 3;
      const float s = red[0][l][q] + red[1][l][q] + red[2][l][q] + red[3][l][q];
      const int bl2 = (l >> 4) * 4 + q;   // C/D row mapping -> b-local
      const int r = l & 15;               // C/D col mapping -> j-local
      gsm[bl2][r] = s + pre_s[r][bl2];
    }
    __syncthreads();

    // cell update: 16 threads (lanes 0..15 of wave0), 4 cells each
    if (tid < 16) {
      const int b = half * 16 + tid;
      union { ushort4 s; uint2 v; } hh, hl;
      u16* hhp = &hh.s.x; u16* hlp = &hl.s.x;
#pragma unroll
      for (int il = 0; il < 4; ++il) {
        const float gi = gsm[tid][il];
        const float gf = gsm[tid][4 + il];
        const float gg = gsm[tid][8 + il];
        const float go = gsm[tid][12 + il];
        const float cn = sigf(gf) * creg[il] + sigf(gi) * tanhf(gg);
        const float hn = sigf(go) * tanhf(cn);
        creg[il] = cn;
        const u16 h16 = f2bf(hn);
        hhp[il] = h16;
        hlp[il] = f2bf(hn - bf2f(h16));
      }
      store8_mall(&Ahi[(size_t)(t * B_ + b) * H_ + 4 * g], hh.v);
      store8_mall(&Alo[(size_t)(t * B_ + b) * H_ + 4 * g], hl.v);
      asm volatile("s_waitcnt vmcnt(0)" ::: "memory");  // stores ack'd at MALL
    }
    __syncthreads();   // all h stores of this block complete

    if (t != T_ - 1) {
      // signal arrival (relaxed: ordering already ensured by vmcnt+barrier)
      if (tid == 0)
        __hip_atomic_store(&flags[(t * 2 + half) * NG_ + g], 1,
                           __ATOMIC_RELAXED, __HIP_MEMORY_SCOPE_AGENT);
      // prefetch next preT slice under the spin
      pv = preT[(size_t)(t + 1) * G4_ * B_ + pre_base];
      // spin: wave0 polls own half's 256 flags (4/lane, relaxed agent loads)
      if (wave == 0) {
        const int* fp = flags + (t * 2 + half) * NG_ + lane * 4;
        for (;;) {
          const int a  = __hip_atomic_load(fp + 0, __ATOMIC_RELAXED, __HIP_MEMORY_SCOPE_AGENT);
          const int b2 = __hip_atomic_load(fp + 1, __ATOMIC_RELAXED, __HIP_MEMORY_SCOPE_AGENT);
          const int c  = __hip_atomic_load(fp + 2, __ATOMIC_RELAXED, __HIP_MEMORY_SCOPE_AGENT);
          const int d  = __hip_atomic_load(fp + 3, __ATOMIC_RELAXED, __HIP_MEMORY_SCOPE_AGENT);
          if (__all((a & b2 & c & d) != 0)) break;
        }
      }
      __syncthreads();   // release all waves; also orders next h loads after spin
    }
  }
}

// ---------------------------------------------------------------------------
// K5: argmax over V per row m; predic[b][t] = argmax_v logits[m][v], first max.
// ---------------------------------------------------------------------------
__global__ __launch_bounds__(256) void argmax_rows(const float* __restrict__ logits,
                                                   float* __restrict__ predic) {
  const int m = blockIdx.x;  // 0..2047
  const float* row = logits + (size_t)m * V_;
  const int tid = threadIdx.x;
  float bv = -3.402823466e38f;
  int bi = V_;
  for (int v = tid; v < V_; v += 256) {
    float x = row[v];
    if (x > bv) { bv = x; bi = v; }   // ascending v => first-max kept
  }
  __shared__ float sv[256];
  __shared__ int si[256];
  sv[tid] = bv; si[tid] = bi;
  __syncthreads();
  for (int s = 128; s > 0; s >>= 1) {
    if (tid < s) {
      if (sv[tid + s] > sv[tid] ||
          (sv[tid + s] == sv[tid] && si[tid + s] < si[tid])) {
        sv[tid] = sv[tid + s];
        si[tid] = si[tid + s];
      }
    }
    __syncthreads();
  }
  if (tid == 0) {
    int t = m >> 5, b = m & 31;
    predic[b * T_ + t] = (float)si[0];
  }
}

// ---------------------------------------------------------------------------
extern "C" void kernel_launch(void* const* d_in, const int* in_sizes, int n_in,
                              void* d_out, int out_size, void* d_ws, size_t ws_size,
                              hipStream_t stream) {
  const float* enc  = (const float*)d_in[0];
  const int*   gt   = (const int*)d_in[1];
  const float* emb  = (const float*)d_in[2];
  const float* W_ih = (const float*)d_in[3];
  const float* W_hh = (const float*)d_in[4];
  const float* b_ih = (const float*)d_in[5];
  const float* b_hh = (const float*)d_in[6];
  const float* W_fc = (const float*)d_in[7];
  const float* b_fc = (const float*)d_in[8];
  // d_in[9]=ssprob=1, d_in[10]=is_train=1 -> teacher forcing always.

  float* out    = (float*)d_out;
  float* logits = out;                          // [2048][32000]
  float* predic = out + (size_t)M_ * V_;        // [32][64]

  // scratch inside d_out (dead before final GEMM overwrites it):
  u16*   Xhi    = (u16*)out;                    // [2048][1536] u16 (3 MB)
  u16*   Xlo    = Xhi + (size_t)M_ * ED_;       // next 3 MB
  float* preT   = out + 4194304;                // [64][4096][32] = 8,388,608 floats

  float* ws     = (float*)d_ws;
  float* bsum   = ws;                           // 4096
  u16*   Ahi    = (u16*)(ws + 4096);            // [2048][1024] u16 (4 MB)
  u16*   Alo    = Ahi + (size_t)M_ * H_;        // 4 MB
  int*   flags  = (int*)(Alo + (size_t)M_ * H_); // [64][2][256] = 128 KB

  hipMemsetAsync(flags, 0, T_ * 2 * NG_ * sizeof(int), stream);

  build_x_split<<<dim3(M_, 6), 256, 0, stream>>>(enc, gt, emb, Xhi, Xlo);
  bias_sum_k<<<16, 256, 0, stream>>>(b_ih, b_hh, bsum);

  // preT[t][j][b] = X @ W_ih^T + (b_ih + b_hh)   (bf16x3 MFMA, transposed out)
  gemm_bf16x3<1><<<dim3(G4_ / 128, M_ / 128), 256, 0, stream>>>(
      Xhi, Xlo, W_ih, bsum, preT, M_, G4_, ED_);

  // all 64 recurrent steps in one persistent kernel (fence-free flag barrier)
  lstm_loop<<<NB_, 256, 0, stream>>>(W_hh, preT, Ahi, Alo, flags);

  // logits = (Ahi+Alo) @ W_fc^T + b_fc   (bf16x3 MFMA)
  gemm_bf16x3<0><<<dim3(V_ / 128, M_ / 128), 256, 0, stream>>>(
      Ahi, Alo, W_fc, b_fc, logits, M_, V_, H_);

  argmax_rows<<<M_, 256, 0, stream>>>(logits, predic);
}